// Round 4
// baseline (367.515 us; speedup 1.0000x reference)
//
#include <hip/hip_runtime.h>

typedef unsigned short u16;
typedef __attribute__((ext_vector_type(8))) short s16x8;
typedef __attribute__((ext_vector_type(4))) float f32x4;
typedef __attribute__((ext_vector_type(4))) unsigned short u16x4;

#define DIMSZ 2048
#define NH    16
#define NKV   4
#define SEQ   2048
#define BB    2
#define HD    128
#define REPF  4
#define SCALE 0.08838834764831845f

__device__ __forceinline__ u16 f2bf(float x) {
  union { float f; unsigned u; } v; v.f = x;
  unsigned r = v.u + 0x7fffu + ((v.u >> 16) & 1u);
  return (u16)(r >> 16);
}
__device__ __forceinline__ float bf2f(u16 x) {
  union { unsigned u; float f; } v; v.u = ((unsigned)x) << 16;
  return v.f;
}
__device__ __forceinline__ unsigned pack2(float a, float b) {
  union { float f; unsigned u; } x, y; x.f = a; y.f = b;
  return ((x.u + 0x8000u) >> 16) | ((y.u + 0x8000u) & 0xffff0000u);
}
__device__ __forceinline__ void gld16(const void* g, void* l) {
  __builtin_amdgcn_global_load_lds(
      (const __attribute__((address_space(1))) unsigned int*)g,
      (__attribute__((address_space(3))) unsigned int*)l, 16, 0, 0);
}

#define BARX __builtin_amdgcn_s_barrier()
#define LG0  do { asm volatile("s_waitcnt lgkmcnt(0)" ::: "memory"); \
                  __builtin_amdgcn_sched_barrier(0); } while (0)
#define VMW(n) asm volatile("s_waitcnt vmcnt(" #n ")" ::: "memory")

// ---------------- x f32 -> bf16 ----------------
__global__ __launch_bounds__(256) void k_cvt(const float* __restrict__ x,
                                             u16* __restrict__ o) {
  int i = (blockIdx.x * 256 + threadIdx.x) * 8;
  float4 a = *(const float4*)(x + i);
  float4 b = *(const float4*)(x + i + 4);
  u16x4 p0 = { f2bf(a.x), f2bf(a.y), f2bf(a.z), f2bf(a.w) };
  u16x4 p1 = { f2bf(b.x), f2bf(b.y), f2bf(b.z), f2bf(b.w) };
  *(u16x4*)(o + i) = p0;
  *(u16x4*)(o + i + 4) = p1;
}

// ---------------- W [K][N] f32 -> Wt [N][K] bf16 ----------------
__global__ __launch_bounds__(256) void k_transpose(const float* __restrict__ W,
                                                   u16* __restrict__ Wt,
                                                   int K, int N) {
  __shared__ float t[32][33];
  int tx = threadIdx.x & 31, ty = threadIdx.x >> 5;
  int r0 = blockIdx.y * 32, c0 = blockIdx.x * 32;
#pragma unroll
  for (int i = 0; i < 32; i += 8)
    t[ty + i][tx] = W[(size_t)(r0 + ty + i) * N + c0 + tx];
  __syncthreads();
#pragma unroll
  for (int i = 0; i < 32; i += 8)
    Wt[(size_t)(c0 + ty + i) * K + r0 + tx] = f2bf(t[tx][ty + i]);
}

// ---------------- 256x256 GEMM, 4-phase/K-tile, counted vmcnt ----------------
// A[M][K] bf16, Bt[N][K] bf16. mode 1: f32 C0[M][N].
// mode 3: fused QKV: n<2048 -> C0 bf16 [M][2048]; n<2560 -> C1 bf16 [M][512];
//         else C2 = V^T [B][KV][HD][SEQ].
__global__ __launch_bounds__(512, 2) void k_gemm256(const u16* __restrict__ A,
                                                    const u16* __restrict__ Bt,
                                                    void* __restrict__ C0,
                                                    void* __restrict__ C1,
                                                    void* __restrict__ C2,
                                                    int M, int N, int K, int mode) {
  __shared__ __align__(16) u16 shA[2][256 * 64];
  __shared__ __align__(16) u16 shB[2][256 * 64];
  const int tid = threadIdx.x;
  const int wave = tid >> 6, lane = tid & 63;
  const int l15 = lane & 15, lh = lane >> 4;
  const int wm = wave >> 2, wn = wave & 3;
  const int m0 = blockIdx.y * 256, n0 = blockIdx.x * 256;

  // staging: per unit (arr, rowblock rb of 64 rows): thread covers
  // row = rb*64 + wave*8 + (lane>>3), granule (lane&7) ^ (row&7); dst linear.
  const int srow = wave * 8 + (lane >> 3);
  const int sgr = ((lane & 7) ^ ((lane >> 3) & 7)) * 8;
  const u16* gA = A + (size_t)(m0 + srow) * K + sgr;
  const u16* gB = Bt + (size_t)(n0 + srow) * K + sgr;

  auto stgA = [&](int rb, int kt, int sl) {
    gld16(gA + (size_t)rb * 64 * K + (size_t)kt * 64, &shA[sl][rb * 4096 + wave * 512]);
  };
  auto stgB = [&](int rb, int kt, int sl) {
    gld16(gB + (size_t)rb * 64 * K + (size_t)kt * 64, &shB[sl][rb * 4096 + wave * 512]);
  };
  // ds_read: global granule gk = ks*4+lh of row rl lives at LDS granule gk^(rl&7)
  auto rdA = [&](int mf, int ks, int sl) -> s16x8 {
    int rl = wm * 128 + mf * 16 + l15;
    return *(const s16x8*)&shA[sl][rl * 64 + (((ks * 4 + lh) ^ (l15 & 7)) * 8)];
  };
  auto rdB = [&](int nf, int ks, int sl) -> s16x8 {
    int rl = wn * 64 + nf * 16 + l15;
    return *(const s16x8*)&shB[sl][rl * 64 + (((ks * 4 + lh) ^ (l15 & 7)) * 8)];
  };

  f32x4 acc[8][4] = {};
  s16x8 afr[4], bfr[4];
  const int NK = K >> 6;

  // prologue: stage tile 0, order B0,B1,B2,B3,A0,A2,A1,A3
  stgB(0, 0, 0); stgB(1, 0, 0); stgB(2, 0, 0); stgB(3, 0, 0);
  stgA(0, 0, 0); stgA(2, 0, 0); stgA(1, 0, 0); stgA(3, 0, 0);
  VMW(2);
  BARX;

  for (int t = 0; t < NK; ++t) {
    const int sl = t & 1, ns = sl ^ 1;
    const bool st = (t + 1 < NK);
    const int kn = t + 1;

    // ---- phase 1: kstep0, m-frags 0-3 ----
#pragma unroll
    for (int nf = 0; nf < 4; nf++) bfr[nf] = rdB(nf, 0, sl);
#pragma unroll
    for (int i = 0; i < 4; i++) afr[i] = rdA(i, 0, sl);
    if (st) { stgB(0, kn, ns); stgB(1, kn, ns); }
    BARX; LG0;
    __builtin_amdgcn_s_setprio(1);
#pragma unroll
    for (int i = 0; i < 4; i++)
#pragma unroll
      for (int nf = 0; nf < 4; nf++)
        acc[i][nf] = __builtin_amdgcn_mfma_f32_16x16x32_bf16(afr[i], bfr[nf], acc[i][nf], 0, 0, 0);
    __builtin_amdgcn_s_setprio(0);
    if (st) VMW(2); else VMW(0);   // force prev tile's A1,A3 before phase 2
    BARX;

    // ---- phase 2: kstep0, m-frags 4-7 ----
#pragma unroll
    for (int i = 0; i < 4; i++) afr[i] = rdA(4 + i, 0, sl);
    if (st) { stgB(2, kn, ns); stgB(3, kn, ns); }
    BARX; LG0;
    __builtin_amdgcn_s_setprio(1);
#pragma unroll
    for (int i = 0; i < 4; i++)
#pragma unroll
      for (int nf = 0; nf < 4; nf++)
        acc[4 + i][nf] = __builtin_amdgcn_mfma_f32_16x16x32_bf16(afr[i], bfr[nf], acc[4 + i][nf], 0, 0, 0);
    __builtin_amdgcn_s_setprio(0);
    BARX;

    // ---- phase 3: kstep1, m-frags 0-3 ----
#pragma unroll
    for (int nf = 0; nf < 4; nf++) bfr[nf] = rdB(nf, 1, sl);
#pragma unroll
    for (int i = 0; i < 4; i++) afr[i] = rdA(i, 1, sl);
    if (st) { stgA(0, kn, ns); stgA(2, kn, ns); }
    BARX; LG0;
    __builtin_amdgcn_s_setprio(1);
#pragma unroll
    for (int i = 0; i < 4; i++)
#pragma unroll
      for (int nf = 0; nf < 4; nf++)
        acc[i][nf] = __builtin_amdgcn_mfma_f32_16x16x32_bf16(afr[i], bfr[nf], acc[i][nf], 0, 0, 0);
    __builtin_amdgcn_s_setprio(0);
    BARX;

    // ---- phase 4: kstep1, m-frags 4-7 ----
#pragma unroll
    for (int i = 0; i < 4; i++) afr[i] = rdA(4 + i, 1, sl);
    if (st) { stgA(1, kn, ns); stgA(3, kn, ns); }
    BARX; LG0;
    __builtin_amdgcn_s_setprio(1);
#pragma unroll
    for (int i = 0; i < 4; i++)
#pragma unroll
      for (int nf = 0; nf < 4; nf++)
        acc[4 + i][nf] = __builtin_amdgcn_mfma_f32_16x16x32_bf16(afr[i], bfr[nf], acc[4 + i][nf], 0, 0, 0);
    __builtin_amdgcn_s_setprio(0);
    if (st) VMW(2);                // units 0-5 of t+1 landed; A1,A3 stay in flight
    BARX;
  }

  // ---- epilogue ----
  if (mode == 1) {
    float* C = (float*)C0;
#pragma unroll
    for (int mf = 0; mf < 8; mf++)
#pragma unroll
      for (int nf = 0; nf < 4; nf++)
#pragma unroll
        for (int r = 0; r < 4; r++) {
          int m = m0 + wm * 128 + mf * 16 + lh * 4 + r;
          int n = n0 + wn * 64 + nf * 16 + l15;
          C[(size_t)m * N + n] = acc[mf][nf][r];
        }
  } else {
    if (n0 < 2048) {
      u16* C = (u16*)C0;
#pragma unroll
      for (int mf = 0; mf < 8; mf++)
#pragma unroll
        for (int nf = 0; nf < 4; nf++)
#pragma unroll
          for (int r = 0; r < 4; r++) {
            int m = m0 + wm * 128 + mf * 16 + lh * 4 + r;
            int n = n0 + wn * 64 + nf * 16 + l15;
            C[(size_t)m * 2048 + n] = f2bf(acc[mf][nf][r]);
          }
    } else if (n0 < 2560) {
      u16* C = (u16*)C1;
#pragma unroll
      for (int mf = 0; mf < 8; mf++)
#pragma unroll
        for (int nf = 0; nf < 4; nf++)
#pragma unroll
          for (int r = 0; r < 4; r++) {
            int m = m0 + wm * 128 + mf * 16 + lh * 4 + r;
            int n = n0 - 2048 + wn * 64 + nf * 16 + l15;
            C[(size_t)m * 512 + n] = f2bf(acc[mf][nf][r]);
          }
    } else {  // V^T: [B][NKV][HD][SEQ]
      u16* C = (u16*)C2;
#pragma unroll
      for (int mf = 0; mf < 8; mf++)
#pragma unroll
        for (int nf = 0; nf < 4; nf++) {
          int n = n0 - 2560 + wn * 64 + nf * 16 + l15;
          int kvh = n >> 7, d = n & 127;
          int m = m0 + wm * 128 + mf * 16 + lh * 4;
          int b = m >> 11, s = m & 2047;
          u16x4 pk = { f2bf(acc[mf][nf][0]), f2bf(acc[mf][nf][1]),
                       f2bf(acc[mf][nf][2]), f2bf(acc[mf][nf][3]) };
          *(u16x4*)&C[(((size_t)b * NKV + kvh) * HD + d) * SEQ + s] = pk;
        }
    }
  }
}

// ---------------- fused RMSNorm + RoPE, in place, one wave per row ----------------
__global__ __launch_bounds__(256) void k_normrope(u16* __restrict__ Q,
                                                  u16* __restrict__ Kb,
                                                  const float* __restrict__ qg,
                                                  const float* __restrict__ kg,
                                                  const float* __restrict__ cosT,
                                                  const float* __restrict__ sinT) {
  int wid = (blockIdx.x * 256 + threadIdx.x) >> 6;
  int lane = threadIdx.x & 63;
  const int NQR = BB * SEQ * NH;
  u16* ptr; const float* g; int s;
  if (wid < NQR) {
    ptr = Q + (size_t)wid * HD; g = qg; s = (wid / NH) % SEQ;
  } else {
    int r2 = wid - NQR;
    ptr = Kb + (size_t)r2 * HD; g = kg; s = (r2 / NKV) % SEQ;
  }
  int d = lane * 2;
  unsigned v = *(const unsigned*)(ptr + d);
  float x0 = bf2f((u16)(v & 0xffff)), x1 = bf2f((u16)(v >> 16));
  float ss = x0 * x0 + x1 * x1;
#pragma unroll
  for (int off = 32; off >= 1; off >>= 1) ss += __shfl_xor(ss, off);
  float rinv = rsqrtf(ss * (1.0f / HD) + 1e-6f);
  float2 gv = *(const float2*)&g[d];
  float n0 = x0 * rinv * gv.x, n1 = x1 * rinv * gv.y;
  float p0 = __shfl_xor(n0, 32), p1 = __shfl_xor(n1, 32);
  float r0 = (lane < 32) ? -p0 : p0;
  float r1 = (lane < 32) ? -p1 : p1;
  float2 cc = *(const float2*)&cosT[s * HD + d];
  float2 sn = *(const float2*)&sinT[s * HD + d];
  float o0 = n0 * cc.x + r0 * sn.x, o1 = n1 * cc.y + r1 * sn.y;
  *(unsigned*)(ptr + d) = (unsigned)f2bf(o0) | ((unsigned)f2bf(o1) << 16);
}

// ---------------- flash attention, causal, GQA: 8 waves, QBLK=128 ----------------
__global__ __launch_bounds__(512, 2) void k_attn(const u16* __restrict__ Q,
                                                 const u16* __restrict__ Kb,
                                                 const u16* __restrict__ Vt,
                                                 u16* __restrict__ O) {
  __shared__ __align__(16) u16 shK[2][64 * 128];   // [kv][d], granule XOR swizzle
  __shared__ __align__(16) u16 shV[2][128 * 64];   // [d][kv], granule XOR swizzle
  __shared__ __align__(16) u16 shP[8][16 * 72];    // per-wave P [q=16][kv=64] pad->72
  const int tid = threadIdx.x, wave = tid >> 6, lane = tid & 63;
  const int l15 = lane & 15, lh = lane >> 4;
  const int bid = blockIdx.x;
  const int qt = 15 - (bid >> 5);       // longest-first dispatch, QBLK=128
  const int bh = bid & 31, b = bh >> 4, h = bh & 15, kvh = h >> 2;
  const int q0w = qt * 128 + wave * 16;

  // Q fragments from global (row = l15, k = kf*32 + lh*8 ..+7)
  const u16* qbase = Q + ((size_t)((size_t)b * SEQ + q0w + l15) * NH + h) * HD;
  s16x8 qf[4];
#pragma unroll
  for (int kf = 0; kf < 4; kf++) qf[kf] = *(const s16x8*)(qbase + kf * 32 + lh * 8);

  // staging (8 waves, 2 gld16 each for K and V)
  const u16* srcK[2]; const u16* srcV[2];
  int dstK[2], dstV[2];
#pragma unroll
  for (int c = 0; c < 2; c++) {
    int rk = c * 32 + wave * 4 + (lane >> 4);
    int gk = (lane & 15) ^ (rk & 7);
    srcK[c] = Kb + ((size_t)((size_t)b * SEQ + rk) * NKV + kvh) * HD + gk * 8;
    dstK[c] = (c * 32 + wave * 4) * 128;
    int rv = c * 64 + wave * 8 + (lane >> 3);
    int gv = (lane & 7) ^ (rv & 7);
    srcV[c] = Vt + ((size_t)((size_t)b * NKV + kvh) * HD + rv) * SEQ + gv * 8;
    dstV[c] = (c * 64 + wave * 8) * 64;
  }

  f32x4 oacc[8] = {};
  float m = -3e38f, l = 0.f;
  const int nt = qt * 2 + 2;
  const int tmask = q0w >> 6;            // first tile needing causal mask (wave-uniform)
  const float SC2 = SCALE * 1.44269504f; // exp2 domain

  // prologue: stage tile 0 into buf 0
#pragma unroll
  for (int c = 0; c < 2; c++) {
    gld16(srcK[c], &shK[0][dstK[c]]);
    gld16(srcV[c], &shV[0][dstV[c]]);
  }
  __syncthreads();

  int buf = 0;
  for (int kt = 0; kt < nt; kt++) {
    if (kt + 1 < nt) {
      const size_t koff = (size_t)(kt + 1) * 64;
#pragma unroll
      for (int c = 0; c < 2; c++) {
        gld16(srcK[c] + koff * (NKV * HD), &shK[buf ^ 1][dstK[c]]);
        gld16(srcV[c] + koff, &shV[buf ^ 1][dstV[c]]);
      }
    }

    // S^T = K Q^T : lane holds q = q0w+l15, k = kt*64 + nf*16 + lh*4 + r
    f32x4 sacc[4] = {};
    __builtin_amdgcn_s_setprio(1);
#pragma unroll
    for (int kf = 0; kf < 4; kf++)
#pragma unroll
      for (int nf = 0; nf < 4; nf++) {
        s16x8 kfr = *(const s16x8*)&shK[buf][(nf * 16 + l15) * 128 + (((kf * 4 + lh) ^ (l15 & 7)) * 8)];
        sacc[nf] = __builtin_amdgcn_mfma_f32_16x16x32_bf16(kfr, qf[kf], sacc[nf], 0, 0, 0);
      }
    __builtin_amdgcn_s_setprio(0);

    const int q = q0w + l15;
    float p[4][4];
    float mx = -3e38f;
    if (kt >= tmask) {
#pragma unroll
      for (int nf = 0; nf < 4; nf++)
#pragma unroll
        for (int r = 0; r < 4; r++) {
          int k = kt * 64 + nf * 16 + lh * 4 + r;
          float s = (k <= q) ? sacc[nf][r] * SC2 : -3e38f;
          p[nf][r] = s; mx = fmaxf(mx, s);
        }
    } else {
#pragma unroll
      for (int nf = 0; nf < 4; nf++)
#pragma unroll
        for (int r = 0; r < 4; r++) {
          float s = sacc[nf][r] * SC2;
          p[nf][r] = s; mx = fmaxf(mx, s);
        }
    }
    mx = fmaxf(mx, __shfl_xor(mx, 16));
    mx = fmaxf(mx, __shfl_xor(mx, 32));

    // defer-max (T13)
    if (!__all(mx - m <= 8.0f)) {
      float mnew = fmaxf(m, mx);
      float alpha = exp2f(m - mnew);
      l *= alpha; m = mnew;
#pragma unroll
      for (int r = 0; r < 4; r++) {
        float ar = __shfl(alpha, (lh << 2) | r);
#pragma unroll
        for (int nf = 0; nf < 8; nf++) oacc[nf][r] *= ar;
      }
    }

    float rs = 0.f;
#pragma unroll
    for (int nf = 0; nf < 4; nf++)
#pragma unroll
      for (int r = 0; r < 4; r++) {
        float pe = exp2f(p[nf][r] - m);
        p[nf][r] = pe; rs += pe;
      }
    rs += __shfl_xor(rs, 16);
    rs += __shfl_xor(rs, 32);
    l += rs;

    u16* pw = &shP[wave][l15 * 72];
#pragma unroll
    for (int nf = 0; nf < 4; nf++) {
      uint2 w2 = { pack2(p[nf][0], p[nf][1]), pack2(p[nf][2], p[nf][3]) };
      *(uint2*)(pw + nf * 16 + lh * 4) = w2;
    }
    LG0;

    // O += P V
    __builtin_amdgcn_s_setprio(1);
#pragma unroll
    for (int kvf = 0; kvf < 2; kvf++) {
      s16x8 pf = *(const s16x8*)&shP[wave][l15 * 72 + kvf * 32 + lh * 8];
#pragma unroll
      for (int nf = 0; nf < 8; nf++) {
        s16x8 vf = *(const s16x8*)&shV[buf][(nf * 16 + l15) * 64 + (((kvf * 4 + lh) ^ (l15 & 7)) * 8)];
        oacc[nf] = __builtin_amdgcn_mfma_f32_16x16x32_bf16(pf, vf, oacc[nf], 0, 0, 0);
      }
    }
    __builtin_amdgcn_s_setprio(0);
    __syncthreads();
    buf ^= 1;
  }

#pragma unroll
  for (int r = 0; r < 4; r++) {
    float lv = __shfl(l, (lh << 2) | r);
    float linv = 1.0f / lv;
    int s = q0w + lh * 4 + r;
    u16* orow = O + ((size_t)((size_t)b * SEQ + s) * NH + h) * HD;
#pragma unroll
    for (int nf = 0; nf < 8; nf++)
      orow[nf * 16 + l15] = f2bf(oacc[nf][r] * linv);
  }
}

extern "C" void kernel_launch(void* const* d_in, const int* in_sizes, int n_in,
                              void* d_out, int out_size, void* d_ws, size_t ws_size,
                              hipStream_t stream) {
  const float* x    = (const float*)d_in[0];
  const float* Wq   = (const float*)d_in[1];
  const float* Wk   = (const float*)d_in[2];
  const float* Wv   = (const float*)d_in[3];
  const float* Wo   = (const float*)d_in[4];
  const float* qg   = (const float*)d_in[5];
  const float* kg   = (const float*)d_in[6];
  const float* cosT = (const float*)d_in[7];
  const float* sinT = (const float*)d_in[8];

  char* ws = (char*)d_ws;
  const size_t MB = 1024 * 1024;
  u16* xb    = (u16*)(ws);               // 16MB: x bf16, reused later as attn-out O
  u16* Wqkvt = (u16*)(ws + 16 * MB);     // 12MB: [Wq^T | Wk^T | Wv^T] rows, [3072][2048]
  u16* Wot   = (u16*)(ws + 28 * MB);     // 8MB
  u16* Qb    = (u16*)(ws + 36 * MB);     // 16MB
  u16* Kbf   = (u16*)(ws + 52 * MB);     // 4MB
  u16* Vt    = (u16*)(ws + 56 * MB);     // 4MB  (total 60MB)
  u16* Ob    = xb;                       // xb dead after QKV GEMM

  k_cvt<<<4096, 256, 0, stream>>>(x, xb);
  k_transpose<<<dim3(DIMSZ / 32, DIMSZ / 32), 256, 0, stream>>>(Wq, Wqkvt, DIMSZ, DIMSZ);
  k_transpose<<<dim3(512 / 32, DIMSZ / 32), 256, 0, stream>>>(Wk, Wqkvt + (size_t)2048 * 2048, DIMSZ, 512);
  k_transpose<<<dim3(512 / 32, DIMSZ / 32), 256, 0, stream>>>(Wv, Wqkvt + (size_t)2560 * 2048, DIMSZ, 512);
  k_transpose<<<dim3(DIMSZ / 32, DIMSZ / 32), 256, 0, stream>>>(Wo, Wot, DIMSZ, DIMSZ);

  // fused QKV projection: N = 2048 (Q) + 512 (K) + 512 (V^T epilogue)
  k_gemm256<<<dim3(12, 16), 512, 0, stream>>>(xb, Wqkvt, Qb, Kbf, Vt,
                                              BB * SEQ, 3072, DIMSZ, 3);

  k_normrope<<<20480, 256, 0, stream>>>(Qb, Kbf, qg, kg, cosT, sinT);
  k_attn<<<512, 512, 0, stream>>>(Qb, Kbf, Vt, Ob);

  k_gemm256<<<dim3(8, 16), 512, 0, stream>>>(Ob, Wot, (float*)d_out, nullptr, nullptr,
                                             BB * SEQ, DIMSZ, DIMSZ, 1);
}

// Round 5
// 349.085 us; speedup vs baseline: 1.0528x; 1.0528x over previous
//
#include <hip/hip_runtime.h>

typedef unsigned short u16;
typedef __attribute__((ext_vector_type(8))) short s16x8;
typedef __attribute__((ext_vector_type(4))) float f32x4;
typedef __attribute__((ext_vector_type(16))) float f32x16;
typedef __attribute__((ext_vector_type(4))) unsigned short u16x4;
typedef __attribute__((ext_vector_type(4))) unsigned int ui32x4;

#define DIMSZ 2048
#define NH    16
#define NKV   4
#define SEQ   2048
#define BB    2
#define HD    128
#define REPF  4
#define SCALE 0.08838834764831845f

__device__ __forceinline__ u16 f2bf(float x) {
  union { float f; unsigned u; } v; v.f = x;
  unsigned r = v.u + 0x7fffu + ((v.u >> 16) & 1u);
  return (u16)(r >> 16);
}
__device__ __forceinline__ float bf2f(u16 x) {
  union { unsigned u; float f; } v; v.u = ((unsigned)x) << 16;
  return v.f;
}
__device__ __forceinline__ void gld16(const void* g, void* l) {
  __builtin_amdgcn_global_load_lds(
      (const __attribute__((address_space(1))) unsigned int*)g,
      (__attribute__((address_space(3))) unsigned int*)l, 16, 0, 0);
}

#define BARX __builtin_amdgcn_s_barrier()
#define LG0  do { asm volatile("s_waitcnt lgkmcnt(0)" ::: "memory"); \
                  __builtin_amdgcn_sched_barrier(0); } while (0)
#define VMW(n) do { asm volatile("s_waitcnt vmcnt(" #n ")" ::: "memory"); \
                    __builtin_amdgcn_sched_barrier(0); } while (0)
#define CVTPK(d, a, b) asm("v_cvt_pk_bf16_f32 %0, %1, %2" : "=v"(d) : "v"(a), "v"(b))
#define SWAP32(a, b)   asm("v_permlane32_swap_b32 %0, %1" : "+v"(a), "+v"(b))

// ---------------- x f32 -> bf16 ----------------
__global__ __launch_bounds__(256) void k_cvt(const float* __restrict__ x,
                                             u16* __restrict__ o) {
  int i = (blockIdx.x * 256 + threadIdx.x) * 8;
  float4 a = *(const float4*)(x + i);
  float4 b = *(const float4*)(x + i + 4);
  u16x4 p0 = { f2bf(a.x), f2bf(a.y), f2bf(a.z), f2bf(a.w) };
  u16x4 p1 = { f2bf(b.x), f2bf(b.y), f2bf(b.z), f2bf(b.w) };
  *(u16x4*)(o + i) = p0;
  *(u16x4*)(o + i + 4) = p1;
}

// ---------------- W [K][N] f32 -> Wt [N][K] bf16 ----------------
__global__ __launch_bounds__(256) void k_transpose(const float* __restrict__ W,
                                                   u16* __restrict__ Wt,
                                                   int K, int N) {
  __shared__ float t[32][33];
  int tx = threadIdx.x & 31, ty = threadIdx.x >> 5;
  int r0 = blockIdx.y * 32, c0 = blockIdx.x * 32;
#pragma unroll
  for (int i = 0; i < 32; i += 8)
    t[ty + i][tx] = W[(size_t)(r0 + ty + i) * N + c0 + tx];
  __syncthreads();
#pragma unroll
  for (int i = 0; i < 32; i += 8)
    Wt[(size_t)(c0 + ty + i) * K + r0 + tx] = f2bf(t[tx][ty + i]);
}

// ---------------- GEMM: BM=256 BN=128 BK=64, 8 waves (4Mx2N), triple-buffer,
// 2 phases/K-tile, prefetch distance 2, single counted vmcnt per tile ----------------
// mode 1: f32 C0[M][N]
// mode 3: fused QKV: n<2048 -> C0 bf16 [M][2048]; n<2560 -> C1 bf16 [M][512];
//         else C2 = V^T [B][KV][HD][SEQ]
__global__ __launch_bounds__(512, 2) void k_gemm(const u16* __restrict__ A,
                                                 const u16* __restrict__ Bt,
                                                 void* __restrict__ C0,
                                                 void* __restrict__ C1,
                                                 void* __restrict__ C2,
                                                 int M, int N, int K, int mode) {
  __shared__ __align__(16) u16 shA[3][256 * 64];
  __shared__ __align__(16) u16 shB[3][128 * 64];
  const int tid = threadIdx.x;
  const int wave = tid >> 6, lane = tid & 63;
  const int l15 = lane & 15, lh = lane >> 4;
  const int wm = wave >> 1, wn = wave & 1;  // 4M x 2N, per-wave 64x64
  const int m0 = blockIdx.y * 256, n0 = blockIdx.x * 128;

  // staging: unit = 64 rows x 64 cols (8KB); thread covers row u*64+srow, swizzled granule
  const int srow = wave * 8 + (lane >> 3);
  const int sgr = ((lane & 7) ^ (srow & 7)) * 8;
  const u16* gA = A + (size_t)(m0 + srow) * K + sgr;
  const u16* gB = Bt + (size_t)(n0 + srow) * K + sgr;

  auto stgA = [&](int u, int kt, int sl) {
    gld16(gA + (size_t)u * 64 * K + (size_t)kt * 64, &shA[sl][u * 4096 + wave * 512]);
  };
  auto stgB = [&](int u, int kt, int sl) {
    gld16(gB + (size_t)u * 64 * K + (size_t)kt * 64, &shB[sl][u * 4096 + wave * 512]);
  };
  auto rdA = [&](int mf, int ks, int sl) -> s16x8 {
    int r = wm * 64 + mf * 16 + l15;
    return *(const s16x8*)&shA[sl][r * 64 + (((ks * 4 + lh) ^ (r & 7)) * 8)];
  };
  auto rdB = [&](int nf, int ks, int sl) -> s16x8 {
    int r = wn * 64 + nf * 16 + l15;
    return *(const s16x8*)&shB[sl][r * 64 + (((ks * 4 + lh) ^ (r & 7)) * 8)];
  };

  f32x4 acc[4][4] = {};
  const int NK = K >> 6;

  // prologue: stage tiles 0 and 1
#pragma unroll
  for (int u = 0; u < 4; u++) stgA(u, 0, 0);
  stgB(0, 0, 0); stgB(1, 0, 0);
#pragma unroll
  for (int u = 0; u < 4; u++) stgA(u, 1, 1);
  stgB(0, 1, 1); stgB(1, 1, 1);
  VMW(6);            // tile 0 landed (6 newest = tile 1)
  BARX;

  int sl = 0, s1 = 1, s2 = 2;
  for (int t = 0; t < NK; ++t) {
    const bool st2 = (t + 2 < NK);
    s16x8 af[4], bf[4];

    // ---- phase 0: kstep 0 ----
#pragma unroll
    for (int i = 0; i < 4; i++) af[i] = rdA(i, 0, sl);
#pragma unroll
    for (int i = 0; i < 4; i++) bf[i] = rdB(i, 0, sl);
    if (st2) { stgA(0, t + 2, s2); stgA(1, t + 2, s2); stgA(2, t + 2, s2); }
    BARX; LG0;
    __builtin_amdgcn_s_setprio(1);
#pragma unroll
    for (int i = 0; i < 4; i++)
#pragma unroll
      for (int j = 0; j < 4; j++)
        acc[i][j] = __builtin_amdgcn_mfma_f32_16x16x32_bf16(af[i], bf[j], acc[i][j], 0, 0, 0);
    __builtin_amdgcn_s_setprio(0);
    BARX;

    // ---- phase 1: kstep 1 ----
#pragma unroll
    for (int i = 0; i < 4; i++) af[i] = rdA(i, 1, sl);
#pragma unroll
    for (int i = 0; i < 4; i++) bf[i] = rdB(i, 1, sl);
    if (st2) { stgA(3, t + 2, s2); stgB(0, t + 2, s2); stgB(1, t + 2, s2); }
    BARX; LG0;
    __builtin_amdgcn_s_setprio(1);
#pragma unroll
    for (int i = 0; i < 4; i++)
#pragma unroll
      for (int j = 0; j < 4; j++)
        acc[i][j] = __builtin_amdgcn_mfma_f32_16x16x32_bf16(af[i], bf[j], acc[i][j], 0, 0, 0);
    __builtin_amdgcn_s_setprio(0);
    // end-of-tile wait: ensure tile t+1 landed before any wave reads it (after BARX)
    if (t + 2 < NK)      { VMW(6); }
    else if (t + 1 < NK) { VMW(0); }
    BARX;
    int tmp = sl; sl = s1; s1 = s2; s2 = tmp;
  }

  // ---- epilogue ----
  if (mode == 1) {
    float* C = (float*)C0;
#pragma unroll
    for (int mf = 0; mf < 4; mf++)
#pragma unroll
      for (int nf = 0; nf < 4; nf++)
#pragma unroll
        for (int r = 0; r < 4; r++) {
          int m = m0 + wm * 64 + mf * 16 + lh * 4 + r;
          int n = n0 + wn * 64 + nf * 16 + l15;
          C[(size_t)m * N + n] = acc[mf][nf][r];
        }
  } else {
    if (n0 < 2048) {
      u16* C = (u16*)C0;
#pragma unroll
      for (int mf = 0; mf < 4; mf++)
#pragma unroll
        for (int nf = 0; nf < 4; nf++)
#pragma unroll
          for (int r = 0; r < 4; r++) {
            int m = m0 + wm * 64 + mf * 16 + lh * 4 + r;
            int n = n0 + wn * 64 + nf * 16 + l15;
            C[(size_t)m * 2048 + n] = f2bf(acc[mf][nf][r]);
          }
    } else if (n0 < 2560) {
      u16* C = (u16*)C1;
#pragma unroll
      for (int mf = 0; mf < 4; mf++)
#pragma unroll
        for (int nf = 0; nf < 4; nf++)
#pragma unroll
          for (int r = 0; r < 4; r++) {
            int m = m0 + wm * 64 + mf * 16 + lh * 4 + r;
            int n = n0 - 2048 + wn * 64 + nf * 16 + l15;
            C[(size_t)m * 512 + n] = f2bf(acc[mf][nf][r]);
          }
    } else {  // V^T: [B][NKV][HD][SEQ]
      u16* C = (u16*)C2;
#pragma unroll
      for (int mf = 0; mf < 4; mf++)
#pragma unroll
        for (int nf = 0; nf < 4; nf++) {
          int n = n0 - 2560 + wn * 64 + nf * 16 + l15;
          int kvh = n >> 7, d = n & 127;
          int m = m0 + wm * 64 + mf * 16 + lh * 4;
          int b = m >> 11, s = m & 2047;
          u16x4 pk = { f2bf(acc[mf][nf][0]), f2bf(acc[mf][nf][1]),
                       f2bf(acc[mf][nf][2]), f2bf(acc[mf][nf][3]) };
          *(u16x4*)&C[(((size_t)b * NKV + kvh) * HD + d) * SEQ + s] = pk;
        }
    }
  }
}

// ---------------- fused RMSNorm + RoPE, in place, one wave per row ----------------
__global__ __launch_bounds__(256) void k_normrope(u16* __restrict__ Q,
                                                  u16* __restrict__ Kb,
                                                  const float* __restrict__ qg,
                                                  const float* __restrict__ kg,
                                                  const float* __restrict__ cosT,
                                                  const float* __restrict__ sinT) {
  int wid = (blockIdx.x * 256 + threadIdx.x) >> 6;
  int lane = threadIdx.x & 63;
  const int NQR = BB * SEQ * NH;
  u16* ptr; const float* g; int s;
  if (wid < NQR) {
    ptr = Q + (size_t)wid * HD; g = qg; s = (wid / NH) % SEQ;
  } else {
    int r2 = wid - NQR;
    ptr = Kb + (size_t)r2 * HD; g = kg; s = (r2 / NKV) % SEQ;
  }
  int d = lane * 2;
  unsigned v = *(const unsigned*)(ptr + d);
  float x0 = bf2f((u16)(v & 0xffff)), x1 = bf2f((u16)(v >> 16));
  float ss = x0 * x0 + x1 * x1;
#pragma unroll
  for (int off = 32; off >= 1; off >>= 1) ss += __shfl_xor(ss, off);
  float rinv = rsqrtf(ss * (1.0f / HD) + 1e-6f);
  float2 gv = *(const float2*)&g[d];
  float n0 = x0 * rinv * gv.x, n1 = x1 * rinv * gv.y;
  float p0 = __shfl_xor(n0, 32), p1 = __shfl_xor(n1, 32);
  float r0 = (lane < 32) ? -p0 : p0;
  float r1 = (lane < 32) ? -p1 : p1;
  float2 cc = *(const float2*)&cosT[s * HD + d];
  float2 sn = *(const float2*)&sinT[s * HD + d];
  float o0 = n0 * cc.x + r0 * sn.x, o1 = n1 * cc.y + r1 * sn.y;
  *(unsigned*)(ptr + d) = (unsigned)f2bf(o0) | ((unsigned)f2bf(o1) << 16);
}

// ---------------- flash attention, causal, GQA ----------------
// 32x32x16 MFMA, swapped QK^T (S^T = K·Q^T), P kept fully in registers via
// cvt_pk_bf16 + permlane32_swap (T12). 4 waves x 32 q-rows = QBLK 128.
// LDS 64KB -> 2 blocks/CU.
__global__ __launch_bounds__(256, 2) void k_attn(const u16* __restrict__ Q,
                                                 const u16* __restrict__ Kb,
                                                 const u16* __restrict__ Vt,
                                                 u16* __restrict__ O) {
  __shared__ __align__(16) u16 shK[2][64 * 128];   // [kv][hd], granule XOR swizzle
  __shared__ __align__(16) u16 shV[2][128 * 64];   // [d][kv], granule XOR swizzle
  const int tid = threadIdx.x, wave = tid >> 6, lane = tid & 63;
  const int l31 = lane & 31, hi = lane >> 5;
  const int bid = blockIdx.x;
  const int qt = 15 - (bid >> 5);                  // longest-first
  const int bh = bid & 31, b = bh >> 4, h = bh & 15, kvh = h >> 2;
  const int q0w = qt * 128 + wave * 32;
  const int q = q0w + l31;

  // Q B-frags: qf[s] = Q[q][s*16 + hi*8 .. +7]
  const u16* qbase = Q + ((size_t)((size_t)b * SEQ + q) * NH + h) * HD + hi * 8;
  s16x8 qf[8];
#pragma unroll
  for (int s = 0; s < 8; s++) qf[s] = *(const s16x8*)(qbase + s * 16);

  // staging addresses
  const u16* srcK[4]; const u16* srcV[4]; int dstK[4], dstV[4];
#pragma unroll
  for (int u = 0; u < 4; u++) {
    int rk = u * 16 + wave * 4 + (lane >> 4);
    int gk = (lane & 15) ^ (rk & 7);
    srcK[u] = Kb + ((size_t)((size_t)b * SEQ + rk) * NKV + kvh) * HD + gk * 8;
    dstK[u] = (u * 16 + wave * 4) * 128;
    int rv = u * 32 + wave * 8 + (lane >> 3);
    int gv = (lane & 7) ^ (rv & 7);
    srcV[u] = Vt + ((size_t)((size_t)b * NKV + kvh) * HD + rv) * SEQ + gv * 8;
    dstV[u] = (u * 32 + wave * 8) * 64;
  }

  f32x16 oacc[4] = {};
  float m = -3e38f, l = 0.f;
  const int nt = qt * 2 + 2;
  const int tmask = q0w >> 6;         // first tile needing causal mask
  const int tlast = (q0w + 31) >> 6;  // last tile this wave computes
  const float SC2 = SCALE * 1.44269504f;

  // prologue: stage tile 0
#pragma unroll
  for (int u = 0; u < 4; u++) { gld16(srcK[u], &shK[0][dstK[u]]); gld16(srcV[u], &shV[0][dstV[u]]); }
  __syncthreads();

  int buf = 0;
  for (int kt = 0; kt < nt; kt++) {
    if (kt + 1 < nt) {
      const size_t ko = (size_t)(kt + 1) * 64;
#pragma unroll
      for (int u = 0; u < 4; u++) {
        gld16(srcK[u] + ko * (NKV * HD), &shK[buf ^ 1][dstK[u]]);
        gld16(srcV[u] + ko, &shV[buf ^ 1][dstV[u]]);
      }
    }

    if (kt <= tlast) {
      // S^T = K · Q^T : lane holds q = q0w + l31; kv = kt*64 + tt*32 + (r&3)+8*(r>>2)+4*hi
      f32x16 sacc[2] = {};
      __builtin_amdgcn_s_setprio(1);
#pragma unroll
      for (int s = 0; s < 8; s++)
#pragma unroll
        for (int tt = 0; tt < 2; tt++) {
          int r = tt * 32 + l31;
          s16x8 kf = *(const s16x8*)&shK[buf][r * 128 + (((s * 2 + hi) ^ (r & 7)) * 8)];
          sacc[tt] = __builtin_amdgcn_mfma_f32_32x32x16_bf16(kf, qf[s], sacc[tt], 0, 0, 0);
        }
      __builtin_amdgcn_s_setprio(0);

      float pv[2][16];
      float mx = -3e38f;
      const int kbase = kt * 64 + 4 * hi;
      if (kt >= tmask) {
#pragma unroll
        for (int tt = 0; tt < 2; tt++)
#pragma unroll
          for (int r = 0; r < 16; r++) {
            int kvv = kbase + tt * 32 + (r & 3) + 8 * (r >> 2);
            float v = (kvv <= q) ? sacc[tt][r] * SC2 : -3e38f;
            pv[tt][r] = v; mx = fmaxf(mx, v);
          }
      } else {
#pragma unroll
        for (int tt = 0; tt < 2; tt++)
#pragma unroll
          for (int r = 0; r < 16; r++) {
            float v = sacc[tt][r] * SC2;
            pv[tt][r] = v; mx = fmaxf(mx, v);
          }
      }
      mx = fmaxf(mx, __shfl_xor(mx, 32));

      // defer-max (T13)
      if (!__all(mx - m <= 8.0f)) {
        float mnew = fmaxf(m, mx);
        float al = exp2f(m - mnew);
        l *= al; m = mnew;
#pragma unroll
        for (int dt = 0; dt < 4; dt++)
#pragma unroll
          for (int r = 0; r < 16; r++) oacc[dt][r] *= al;
      }

      float rs = 0.f;
#pragma unroll
      for (int tt = 0; tt < 2; tt++)
#pragma unroll
        for (int r = 0; r < 16; r++) {
          float pe = exp2f(pv[tt][r] - m);
          pv[tt][r] = pe; rs += pe;
        }
      rs += __shfl_xor(rs, 32);
      l += rs;

      // P -> bf16 B-frags fully in-register: per (tt,half): 4 cvt_pk + 2 permlane32_swap
      s16x8 pa[4];
#pragma unroll
      for (int tt = 0; tt < 2; tt++)
#pragma unroll
        for (int hf = 0; hf < 2; hf++) {
          unsigned w0, w1, w2, w3;
          CVTPK(w0, pv[tt][hf * 8 + 0], pv[tt][hf * 8 + 1]);
          CVTPK(w1, pv[tt][hf * 8 + 2], pv[tt][hf * 8 + 3]);
          CVTPK(w2, pv[tt][hf * 8 + 4], pv[tt][hf * 8 + 5]);
          CVTPK(w3, pv[tt][hf * 8 + 6], pv[tt][hf * 8 + 7]);
          SWAP32(w0, w2);   // w0 -> word0 (lo:hi0.pk01|hi:hi0.pk45), w2 -> word2
          SWAP32(w1, w3);   // w1 -> word1, w3 -> word3
          ui32x4 t4 = { w0, w1, w2, w3 };
          pa[tt * 2 + hf] = *(s16x8*)&t4;
        }

      // O^T += V^T · P^T  (A = V^T rows d from LDS, B = P rows q from regs)
      __builtin_amdgcn_s_setprio(1);
#pragma unroll
      for (int sp = 0; sp < 4; sp++)
#pragma unroll
        for (int dt = 0; dt < 4; dt++) {
          int r = dt * 32 + l31;
          s16x8 vf = *(const s16x8*)&shV[buf][r * 64 + (((sp * 2 + hi) ^ (r & 7)) * 8)];
          oacc[dt] = __builtin_amdgcn_mfma_f32_32x32x16_bf16(vf, pa[sp], oacc[dt], 0, 0, 0);
        }
      __builtin_amdgcn_s_setprio(0);
    }

    __syncthreads();
    buf ^= 1;
  }

  // epilogue: O[q][d], d = dt*32 + 8*rg + 4*hi + (0..3)
  float linv = 1.0f / l;
  u16* orow = O + ((size_t)((size_t)b * SEQ + q) * NH + h) * HD;
#pragma unroll
  for (int dt = 0; dt < 4; dt++)
#pragma unroll
    for (int rg = 0; rg < 4; rg++) {
      int d = dt * 32 + 8 * rg + 4 * hi;
      u16x4 pk4 = { f2bf(oacc[dt][rg * 4 + 0] * linv), f2bf(oacc[dt][rg * 4 + 1] * linv),
                    f2bf(oacc[dt][rg * 4 + 2] * linv), f2bf(oacc[dt][rg * 4 + 3] * linv) };
      *(u16x4*)(orow + d) = pk4;
    }
}

extern "C" void kernel_launch(void* const* d_in, const int* in_sizes, int n_in,
                              void* d_out, int out_size, void* d_ws, size_t ws_size,
                              hipStream_t stream) {
  const float* x    = (const float*)d_in[0];
  const float* Wq   = (const float*)d_in[1];
  const float* Wk   = (const float*)d_in[2];
  const float* Wv   = (const float*)d_in[3];
  const float* Wo   = (const float*)d_in[4];
  const float* qg   = (const float*)d_in[5];
  const float* kg   = (const float*)d_in[6];
  const float* cosT = (const float*)d_in[7];
  const float* sinT = (const float*)d_in[8];

  char* ws = (char*)d_ws;
  const size_t MB = 1024 * 1024;
  u16* xb    = (u16*)(ws);               // 16MB: x bf16, reused later as attn-out O
  u16* Wqkvt = (u16*)(ws + 16 * MB);     // 12MB: [Wq^T | Wk^T | Wv^T] rows, [3072][2048]
  u16* Wot   = (u16*)(ws + 28 * MB);     // 8MB
  u16* Qb    = (u16*)(ws + 36 * MB);     // 16MB
  u16* Kbf   = (u16*)(ws + 52 * MB);     // 4MB
  u16* Vt    = (u16*)(ws + 56 * MB);     // 4MB  (total 60MB)
  u16* Ob    = xb;                       // xb dead after QKV GEMM

  k_cvt<<<4096, 256, 0, stream>>>(x, xb);
  k_transpose<<<dim3(DIMSZ / 32, DIMSZ / 32), 256, 0, stream>>>(Wq, Wqkvt, DIMSZ, DIMSZ);
  k_transpose<<<dim3(512 / 32, DIMSZ / 32), 256, 0, stream>>>(Wk, Wqkvt + (size_t)2048 * 2048, DIMSZ, 512);
  k_transpose<<<dim3(512 / 32, DIMSZ / 32), 256, 0, stream>>>(Wv, Wqkvt + (size_t)2560 * 2048, DIMSZ, 512);
  k_transpose<<<dim3(DIMSZ / 32, DIMSZ / 32), 256, 0, stream>>>(Wo, Wot, DIMSZ, DIMSZ);

  // fused QKV projection: N = 2048 (Q) + 512 (K) + 512 (V^T epilogue)
  k_gemm<<<dim3(24, 16), 512, 0, stream>>>(xb, Wqkvt, Qb, Kbf, Vt,
                                           BB * SEQ, 3072, DIMSZ, 3);

  k_normrope<<<20480, 256, 0, stream>>>(Qb, Kbf, qg, kg, cosT, sinT);
  k_attn<<<512, 256, 0, stream>>>(Qb, Kbf, Vt, Ob);

  k_gemm<<<dim3(16, 16), 512, 0, stream>>>(Ob, Wot, (float*)d_out, nullptr, nullptr,
                                           BB * SEQ, DIMSZ, DIMSZ, 1);
}